// Round 6
// baseline (202.378 us; speedup 1.0000x reference)
//
#include <hip/hip_runtime.h>
#include <hip/hip_bf16.h>
#include <stdint.h>

typedef short v8s __attribute__((ext_vector_type(8)));
typedef float v4f __attribute__((ext_vector_type(4)));
typedef float v16f __attribute__((ext_vector_type(16)));

#define N_EMBD 1024
#define HEAD 128
#define TOKENS 16384   // 8*2048
#define T_SEQ 2048
#define BATCH 8
#define BPB 96         // attn blocks/batch: sum_{qt2=0}^{15} ceil((2qt2+2)/3)

__device__ __forceinline__ short f2bf(float f) {
    union { float f; uint32_t u; } c; c.f = f;
    uint32_t u = c.u;
    uint32_t r = (u + 0x7fffu + ((u >> 16) & 1u)) >> 16;
    return (short)r;
}

__device__ __forceinline__ float bf2f(short s) {
    union { uint32_t u; float f; } c; c.u = ((uint32_t)(uint16_t)s) << 16;
    return c.f;
}

// ---------------- kernel 1: W transpose + bf16 convert ----------------
__global__ __launch_bounds__(256)
void wt_kernel(const float* __restrict__ Wq, const float* __restrict__ Wk,
               const float* __restrict__ Wv, short* __restrict__ wt) {
    int tid = blockIdx.x * 256 + threadIdx.x;
    int w   = tid >> 17;
    int rem = tid & 131071;                          // c*128 + h
    int c = rem >> 7, h = rem & 127;
    const float* src = (w == 0) ? Wq : ((w == 1) ? Wk : Wv);
    wt[w * 131072 + h * 1024 + c] = f2bf(src[rem]);
}

// ---------------- kernel 2: QKV GEMM v2 ----------------
// BM=128, BN=128, BK=64, 16 iters, dbuf stride-72, 1 barrier/iter, reg prefetch.
// 384 blocks, XCD-grouped: the 3 w-siblings of an x tile co-resident per XCD.
// Wave-tile 64x64 (2x2 of 32x32x16) -> 1.0 LDS-read per MFMA.
__global__ __launch_bounds__(256, 2)
void qkv_gemm(const float* __restrict__ x, const short* __restrict__ wt,
              short* __restrict__ qkv, short* __restrict__ vT) {
    const int bid = blockIdx.x;                  // 0..383
    const int xcd = bid & 7, q = bid >> 3;       // q 0..47
    const int mtl = q / 3, w = q % 3;
    const int mt  = xcd * 16 + mtl;
    const int m0  = mt * 128;

    __shared__ short smem[2][256 * 72];          // per buf: sA rows 0..127 | sB rows 0..127

    const int t = threadIdx.x;
    const int wv = t >> 6, lane = t & 63;
    const int l31 = lane & 31, l1 = lane >> 5;
    const int wm = wv & 1, wn = wv >> 1;

    const short* wtw = wt + w * 131072;

    // staging coords: A = 128x64 fp32 (2048 float4, 8/thread); B = 128x64 bf16 (1024 16B, 4/thread)
    const int ar = t >> 4, ac = t & 15;          // A: row ar+16*i, float4-col ac
    const int br = t >> 3, bc = t & 7;           // B: row br+32*i, 16B-col bc
    const float* aptr = x + (size_t)(m0 + ar) * 1024 + ac * 4;
    const short* bptr = wtw + br * 1024 + bc * 8;

    float4 af[8]; uint4 bfr[4];
    for (int i = 0; i < 8; ++i) af[i] = *(const float4*)(aptr + (size_t)i * 16 * 1024);
    for (int i = 0; i < 4; ++i) bfr[i] = *(const uint4*)(bptr + (size_t)i * 32 * 1024);

    v16f acc[2][2];
    for (int i = 0; i < 16; ++i) {
        acc[0][0][i] = 0.f; acc[0][1][i] = 0.f; acc[1][0][i] = 0.f; acc[1][1][i] = 0.f;
    }

    // write stage 0
    {
        short* sA = smem[0]; short* sB = smem[0] + 128 * 72;
        for (int i = 0; i < 8; ++i) {
            union { short s[4]; uint64_t u; } p;
            p.s[0] = f2bf(af[i].x); p.s[1] = f2bf(af[i].y);
            p.s[2] = f2bf(af[i].z); p.s[3] = f2bf(af[i].w);
            *(uint64_t*)&sA[(i * 16 + ar) * 72 + ac * 4] = p.u;
        }
        for (int i = 0; i < 4; ++i)
            *(uint4*)&sB[(i * 32 + br) * 72 + bc * 8] = bfr[i];
    }

    for (int it = 0; it < 16; ++it) {
        if (it < 15) {                            // prefetch next K-slice into regs
            int kk = (it + 1) * 64;
            for (int i = 0; i < 8; ++i) af[i] = *(const float4*)(aptr + (size_t)i * 16 * 1024 + kk);
            for (int i = 0; i < 4; ++i) bfr[i] = *(const uint4*)(bptr + (size_t)i * 32 * 1024 + kk);
        }
        __syncthreads();                          // buf[it&1] visible
        const short* sA = smem[it & 1];
        const short* sB = smem[it & 1] + 128 * 72;
        for (int ks = 0; ks < 4; ++ks) {
            v8s a0 = *(const v8s*)&sA[(wm * 64 + l31) * 72 + ks * 16 + l1 * 8];
            v8s a1 = *(const v8s*)&sA[(wm * 64 + 32 + l31) * 72 + ks * 16 + l1 * 8];
            v8s b0 = *(const v8s*)&sB[(wn * 64 + l31) * 72 + ks * 16 + l1 * 8];
            v8s b1 = *(const v8s*)&sB[(wn * 64 + 32 + l31) * 72 + ks * 16 + l1 * 8];
            acc[0][0] = __builtin_amdgcn_mfma_f32_32x32x16_bf16(a0, b0, acc[0][0], 0, 0, 0);
            acc[0][1] = __builtin_amdgcn_mfma_f32_32x32x16_bf16(a0, b1, acc[0][1], 0, 0, 0);
            acc[1][0] = __builtin_amdgcn_mfma_f32_32x32x16_bf16(a1, b0, acc[1][0], 0, 0, 0);
            acc[1][1] = __builtin_amdgcn_mfma_f32_32x32x16_bf16(a1, b1, acc[1][1], 0, 0, 0);
        }
        if (it < 15) {                            // convert + write next stage
            short* nA = smem[(it + 1) & 1];
            short* nB = smem[(it + 1) & 1] + 128 * 72;
            for (int i = 0; i < 8; ++i) {
                union { short s[4]; uint64_t u; } p;
                p.s[0] = f2bf(af[i].x); p.s[1] = f2bf(af[i].y);
                p.s[2] = f2bf(af[i].z); p.s[3] = f2bf(af[i].w);
                *(uint64_t*)&nA[(i * 16 + ar) * 72 + ac * 4] = p.u;
            }
            for (int i = 0; i < 4; ++i)
                *(uint4*)&nB[(i * 32 + br) * 72 + bc * 8] = bfr[i];
        }
    }

    // epilogue. 32x32 C-layout: col = l31 (in tile), row m = (reg&3) + 8*(reg>>2) + 4*l1
    if (w < 2) {
        short* outw = qkv + (size_t)w * TOKENS * HEAD;
        for (int mi = 0; mi < 2; ++mi)
            for (int ni = 0; ni < 2; ++ni) {
                int col = wn * 64 + ni * 32 + l31;
                for (int reg = 0; reg < 16; ++reg) {
                    int m = (reg & 3) + 8 * (reg >> 2) + 4 * l1;
                    outw[(size_t)(m0 + wm * 64 + mi * 32 + m) * HEAD + col] = f2bf(acc[mi][ni][reg]);
                }
            }
    } else {
        __syncthreads();
        short* sT = (short*)smem;    // [128 d][stride 136], tokens 0..127
        for (int mi = 0; mi < 2; ++mi)
            for (int ni = 0; ni < 2; ++ni) {
                int col = wn * 64 + ni * 32 + l31;
                for (int g = 0; g < 4; ++g) {
                    union { short s[4]; uint64_t u; } pk;
                    for (int r = 0; r < 4; ++r) pk.s[r] = f2bf(acc[mi][ni][g * 4 + r]);
                    *(uint64_t*)&sT[col * 136 + wm * 64 + mi * 32 + 8 * g + 4 * l1] = pk.u;
                }
            }
        __syncthreads();
        for (int i = 0; i < 8; ++i) {            // 128 cols x 128 tokens, 2048 16B chunks
            int c = i * 256 + t;
            int col = c >> 4, c8 = c & 15;
            uint4 d = *(const uint4*)(&sT[col * 136 + c8 * 8]);
            *(uint4*)(&vT[(size_t)col * TOKENS + m0 + c8 * 8]) = d;
        }
    }
}

// ---------------- kernel 3: flash attention, S^T swap + K/V reg prefetch ----------------
__global__ __launch_bounds__(256)
void attn_kernel(const short* __restrict__ qb, const short* __restrict__ kb,
                 const short* __restrict__ vT, short* __restrict__ po,
                 float* __restrict__ pl) {
    const int bid = blockIdx.x;
    const int b  = bid & 7;
    const int r0 = bid >> 3;        // 0..95
    int qt2 = 0, c0 = 0;
    for (;;) { int sz = (2 * qt2 + 4) / 3; if (r0 < c0 + sz) break; c0 += sz; ++qt2; }
    const int s = r0 - c0;
    const int q0 = qt2 * 128;
    const int nkt = 2 * qt2 + 2;
    const int kt0 = s * 3;
    const int kt1 = (kt0 + 3 < nkt) ? (kt0 + 3) : nkt;

    __shared__ short sK[64 * 128];    // swizzled 16B chunks
    __shared__ short sV[128 * 64];    // V^T [d][key], swizzled
    __shared__ short sP[128 * 72];    // P [qrow][key], stride 72

    const int t = threadIdx.x;
    const int wv = t >> 6, lane = t & 63, ln = lane & 15, qd = lane >> 4;
    const int wrow0 = q0 + wv * 32;

    v8s qf[2][4];
    for (int qg = 0; qg < 2; ++qg) {
        const short* qrow = qb + ((size_t)(b * T_SEQ + wrow0 + qg * 16 + ln)) * HEAD;
        for (int ks = 0; ks < 4; ++ks)
            qf[qg][ks] = *(const v8s*)(qrow + ks * 32 + qd * 8);
    }

    // prefetch bases (per-thread staging coords identical to R5's staging loops)
    const short* kpb = kb + ((size_t)(b * T_SEQ + kt0 * 64 + (t >> 4))) * HEAD + (t & 15) * 8;
    const short* vpb = vT + (size_t)(t >> 3) * TOKENS + b * T_SEQ + kt0 * 64 + (t & 7) * 8;
    uint4 kpre[4], vpre[4];
    for (int i = 0; i < 4; ++i) {
        kpre[i] = *(const uint4*)(kpb + (size_t)i * 16 * HEAD);
        vpre[i] = *(const uint4*)(vpb + (size_t)i * 32 * TOKENS);
    }

    v4f o[2][8] = {};
    float rs[2] = {0.f, 0.f};
    const float sc = 1.4426950408889634f / 11.313708498984761f;  // log2e / sqrt(128)

    for (int kt = kt0; kt < kt1; ++kt) {
        __syncthreads();                         // also drains prefetched loads
        // ds_write staged K tile: row = i*16 + (t>>4), ch = t&15 (swizzled)
        for (int i = 0; i < 4; ++i) {
            int row = i * 16 + (t >> 4), ch = t & 15;
            int sch = (ch & 8) | ((ch ^ row) & 7);
            *(uint4*)(&sK[row * 128 + sch * 8]) = kpre[i];
        }
        // ds_write staged V tile: dd = i*32 + (t>>3), ch = t&7 (swizzled)
        for (int i = 0; i < 4; ++i) {
            int dd = i * 32 + (t >> 3), ch = t & 7;
            *(uint4*)(&sV[dd * 64 + ((ch ^ dd) & 7) * 8]) = vpre[i];
        }
        __syncthreads();

        if (kt + 1 < kt1) {                      // issue next-tile loads (drain at next barrier)
            int dk = (kt + 1 - kt0);
            for (int i = 0; i < 4; ++i) {
                kpre[i] = *(const uint4*)(kpb + (size_t)i * 16 * HEAD + (size_t)dk * 64 * HEAD);
                vpre[i] = *(const uint4*)(vpb + (size_t)i * 32 * TOKENS + dk * 64);
            }
        }

        if (kt * 64 >= wrow0 + 32) continue;     // wave fully masked

        // S^T: A = K fragments, B = Q fragments
        v4f st[2][4] = {};
        for (int ni = 0; ni < 4; ++ni) {
            int krow = ni * 16 + ln;
            for (int ks = 0; ks < 4; ++ks) {
                int ch = ks * 4 + qd;
                v8s kf = *(const v8s*)&sK[krow * 128 + ((ch & 8) | ((ch ^ krow) & 7)) * 8];
                st[0][ni] = __builtin_amdgcn_mfma_f32_16x16x32_bf16(kf, qf[0][ks], st[0][ni], 0, 0, 0);
                st[1][ni] = __builtin_amdgcn_mfma_f32_16x16x32_bf16(kf, qf[1][ks], st[1][ni], 0, 0, 0);
            }
        }

        // softmax: lane holds qrow=ln, key = ni*16 + qd*4 + r -> b64 P writes
        const bool needMask = (kt * 64 + 63 > wrow0);
        for (int qg = 0; qg < 2; ++qg) {
            int prow = wv * 32 + qg * 16 + ln;
            int qrow_g = wrow0 + qg * 16 + ln;
            for (int ni = 0; ni < 4; ++ni) {
                union { short s[4]; uint64_t u; } pk;
                for (int r = 0; r < 4; ++r) {
                    float p = exp2f(st[qg][ni][r] * sc);
                    int kg = kt * 64 + ni * 16 + qd * 4 + r;
                    if (needMask && kg > qrow_g) p = 0.f;
                    rs[qg] += p;
                    pk.s[r] = f2bf(p);
                }
                *(uint64_t*)(&sP[prow * 72 + ni * 16 + qd * 4]) = pk.u;
            }
        }

        // O^T += : A = V fragments, B = P fragments (same-wave sP rows, in-order)
        for (int kk2 = 0; kk2 < 2; ++kk2) {
            v8s pf0 = *(const v8s*)&sP[(wv * 32 + ln) * 72 + kk2 * 32 + qd * 8];
            v8s pf1 = *(const v8s*)&sP[(wv * 32 + 16 + ln) * 72 + kk2 * 32 + qd * 8];
            for (int oni = 0; oni < 8; ++oni) {
                int dd = oni * 16 + ln;
                int ch = kk2 * 4 + qd;
                v8s vf = *(const v8s*)&sV[dd * 64 + ((ch ^ dd) & 7) * 8];
                o[0][oni] = __builtin_amdgcn_mfma_f32_16x16x32_bf16(vf, pf0, o[0][oni], 0, 0, 0);
                o[1][oni] = __builtin_amdgcn_mfma_f32_16x16x32_bf16(vf, pf1, o[1][oni], 0, 0, 0);
            }
        }
    }

    // row sums: reduce across qd lanes (xor 16, 32)
    float lsum[2];
    for (int qg = 0; qg < 2; ++qg) {
        float v = rs[qg];
        v += __shfl_xor(v, 16);
        v += __shfl_xor(v, 32);
        lsum[qg] = v;
    }

    short* pob = po + (size_t)bid * 128 * 128;
    for (int qg = 0; qg < 2; ++qg)
        for (int oni = 0; oni < 8; ++oni) {
            union { short s[4]; uint2 u; } pk;
            for (int r = 0; r < 4; ++r) pk.s[r] = f2bf(o[qg][oni][r]);
            *(uint2*)(&pob[(((qg * 8 + oni) * 4 + wv) * 64 + lane) * 4]) = pk.u;
        }
    if (lane < 16)
        for (int qg = 0; qg < 2; ++qg)
            pl[bid * 128 + wv * 32 + qg * 16 + lane] = lsum[qg];
}

// ---------------- kernel 4: combine splits ----------------
__global__ __launch_bounds__(256)
void combine_kernel(const short* __restrict__ po, const float* __restrict__ pl,
                    float* __restrict__ out) {
    const int bid = blockIdx.x;          // 512: b<<6 | qt2<<2 | qh<<1 | dh
    const int dh  = bid & 1;
    const int qh  = (bid >> 1) & 1;
    const int qt2 = (bid >> 2) & 15;
    const int b   = bid >> 6;
    int cum = 0;
    for (int j = 0; j < qt2; ++j) cum += (2 * j + 4) / 3;
    const int S = (2 * qt2 + 4) / 3;

    const int t = threadIdx.x;
    const int wv = t >> 6, lane = t & 63, ln = lane & 15, qd = lane >> 4;

    float l = 0.f;
    float accv[4][4] = {};

    for (int si = 0; si < S; ++si) {
        int slot = (cum + si) * 8 + b;
        l += pl[slot * 128 + wv * 32 + qh * 16 + ln];
        const short* pob = po + (size_t)slot * 16384;
        for (int oi = 0; oi < 4; ++oi) {
            int oni = dh * 4 + oi;
            union { short s[4]; uint2 u; } pk;
            pk.u = *(const uint2*)(&pob[(((qh * 8 + oni) * 4 + wv) * 64 + lane) * 4]);
            for (int r = 0; r < 4; ++r) accv[oi][r] += bf2f(pk.s[r]);
        }
    }
    float inv = 1.f / l;
    // lane holds qrow = ln, d = (dh*4+oi)*16 + qd*4 + r
    float* ob = out + ((size_t)(b * T_SEQ) + qt2 * 128 + wv * 32 + qh * 16 + ln) * HEAD;
    for (int oi = 0; oi < 4; ++oi) {
        float4 o4 = make_float4(accv[oi][0] * inv, accv[oi][1] * inv,
                                accv[oi][2] * inv, accv[oi][3] * inv);
        *(float4*)(ob + (dh * 4 + oi) * 16 + qd * 4) = o4;
    }
}

extern "C" void kernel_launch(void* const* d_in, const int* in_sizes, int n_in,
                              void* d_out, int out_size, void* d_ws, size_t ws_size,
                              hipStream_t stream) {
    const float* x  = (const float*)d_in[0];
    const float* Wk = (const float*)d_in[1];
    const float* Wq = (const float*)d_in[2];
    const float* Wv = (const float*)d_in[3];
    float* out = (float*)d_out;

    char* ws = (char*)d_ws;
    short* wt = (short*)ws;                               // 768 KB
    short* qb = (short*)(ws + 0x100000u);                 // 4 MB
    short* kb = (short*)(ws + 0x500000u);                 // 4 MB
    short* vT = (short*)(ws + 0x900000u);                 // 4 MB, [128][16384]
    short* po = (short*)(ws + 0xD00000u);                 // 768*32KB = 24 MB
    float* pl = (float*)(ws + 0x2500000u);                // 768*128 f32
    short* qkv = qb;

    wt_kernel<<<1536, 256, 0, stream>>>(Wq, Wk, Wv, wt);
    qkv_gemm<<<384, 256, 0, stream>>>(x, wt, qkv, vT);
    attn_kernel<<<BATCH * BPB, 256, 0, stream>>>(qb, kb, vT, po, pl);
    combine_kernel<<<512, 256, 0, stream>>>(po, pl, out);
}

// Round 7
// 171.670 us; speedup vs baseline: 1.1789x; 1.1789x over previous
//
#include <hip/hip_runtime.h>
#include <hip/hip_bf16.h>
#include <stdint.h>

typedef short v8s __attribute__((ext_vector_type(8)));
typedef float v4f __attribute__((ext_vector_type(4)));
typedef float v16f __attribute__((ext_vector_type(16)));

#define N_EMBD 1024
#define HEAD 128
#define TOKENS 16384   // 8*2048
#define T_SEQ 2048
#define BATCH 8
#define BPB 96         // attn blocks/batch: sum_{qt2=0}^{15} ceil((2qt2+2)/3)

__device__ __forceinline__ short f2bf(float f) {
    union { float f; uint32_t u; } c; c.f = f;
    uint32_t u = c.u;
    uint32_t r = (u + 0x7fffu + ((u >> 16) & 1u)) >> 16;
    return (short)r;
}

__device__ __forceinline__ float bf2f(short s) {
    union { uint32_t u; float f; } c; c.u = ((uint32_t)(uint16_t)s) << 16;
    return c.f;
}

// async global->LDS DMA, 16B per lane; LDS dest = wave-uniform base + lane*16
__device__ __forceinline__ void dma16(const void* g, void* l) {
    __builtin_amdgcn_global_load_lds(
        (const __attribute__((address_space(1))) uint32_t*)g,
        (__attribute__((address_space(3))) uint32_t*)l, 16, 0, 0);
}

// ---------------- kernel 1: W transpose + bf16 convert ----------------
__global__ __launch_bounds__(256)
void wt_kernel(const float* __restrict__ Wq, const float* __restrict__ Wk,
               const float* __restrict__ Wv, short* __restrict__ wt) {
    int tid = blockIdx.x * 256 + threadIdx.x;
    int w   = tid >> 17;
    int rem = tid & 131071;                          // c*128 + h
    int c = rem >> 7, h = rem & 127;
    const float* src = (w == 0) ? Wq : ((w == 1) ? Wk : Wv);
    wt[w * 131072 + h * 1024 + c] = f2bf(src[rem]);
}

// ---------------- kernel 2: QKV GEMM (DMA-B + post-barrier issue) ----------------
// BM=64, BN=128, BK=32, 768 blocks (3/CU), dbuf, 1 barrier/iter.
__global__ __launch_bounds__(256)
void qkv_gemm(const float* __restrict__ x, const short* __restrict__ wt,
              short* __restrict__ qkv, short* __restrict__ vT) {
    const int bid = blockIdx.x;
    const int xcd = bid & 7, q = bid >> 3;
    const int mt  = xcd * 32 + q / 3;
    const int w   = q % 3;
    const int m0  = mt * 64;

    // per buf: A 64 rows x stride 40 (2560 sh) | B 128 rows x 32 sh unpadded (4096 sh)
    __shared__ short smem[2][6656];

    const int t = threadIdx.x;
    const int wv = t >> 6, lane = t & 63;
    const int l31 = lane & 31, l1 = lane >> 5;
    const int wm = wv & 1, wn = wv >> 1;

    const short* wtw = wt + w * 131072;

    const int arow = t >> 3, ac4 = t & 7;
    const float* aptr0 = x + (size_t)(m0 + arow) * 1024 + ac4 * 4;
    const float* aptr1 = x + (size_t)(m0 + arow + 32) * 1024 + ac4 * 4;

    // B DMA coords: chunk c = (wv*2+i)*64+lane; row=c>>2, sch=c&3, src ch=sch^(row&3)
    const int bc0 = (wv * 2) * 64 + lane, bc1 = (wv * 2 + 1) * 64 + lane;
    const int br0 = bc0 >> 2, bh0 = (bc0 & 3) ^ (br0 & 3);
    const int br1 = bc1 >> 2, bh1 = (bc1 & 3) ^ (br1 & 3);
    const short* bsrc0 = wtw + br0 * 1024 + bh0 * 8;
    const short* bsrc1 = wtw + br1 * 1024 + bh1 * 8;

    v16f acc[2];
    for (int i = 0; i < 16; ++i) { acc[0][i] = 0.f; acc[1][i] = 0.f; }

    {   // prologue: stage iter 0 into buf0
        short* sB = smem[0] + 2560;
        dma16(bsrc0, &sB[(wv * 2) * 512]);
        dma16(bsrc1, &sB[(wv * 2 + 1) * 512]);
        float4 a0 = *(const float4*)aptr0;
        float4 a1 = *(const float4*)aptr1;
        short* sA = smem[0];
        union { short s2[4]; uint64_t u; } p0, p1;
        p0.s2[0] = f2bf(a0.x); p0.s2[1] = f2bf(a0.y); p0.s2[2] = f2bf(a0.z); p0.s2[3] = f2bf(a0.w);
        p1.s2[0] = f2bf(a1.x); p1.s2[1] = f2bf(a1.y); p1.s2[2] = f2bf(a1.z); p1.s2[3] = f2bf(a1.w);
        *(uint64_t*)&sA[arow * 40 + ac4 * 4] = p0.u;
        *(uint64_t*)&sA[(arow + 32) * 40 + ac4 * 4] = p1.u;
    }
    __syncthreads();

    float4 af0, af1;
    for (int it = 0; it < 32; ++it) {
        const int cur = it & 1, nxt = cur ^ 1;
        if (it < 31) {     // issue next-iter loads AFTER the barrier
            int kk = (it + 1) * 32;
            short* nB = smem[nxt] + 2560;
            dma16(bsrc0 + kk, &nB[(wv * 2) * 512]);
            dma16(bsrc1 + kk, &nB[(wv * 2 + 1) * 512]);
            af0 = *(const float4*)(aptr0 + kk);
            af1 = *(const float4*)(aptr1 + kk);
        }
        const short* sA = smem[cur];
        const short* sB = smem[cur] + 2560;
        for (int ks = 0; ks < 2; ++ks) {
            v8s a = *(const v8s*)&sA[(wm * 32 + l31) * 40 + ks * 16 + l1 * 8];
            for (int ni = 0; ni < 2; ++ni) {
                int row = wn * 64 + ni * 32 + l31;
                int sch = (ks * 2 + l1) ^ (row & 3);
                v8s b = *(const v8s*)&sB[row * 32 + sch * 8];
                acc[ni] = __builtin_amdgcn_mfma_f32_32x32x16_bf16(a, b, acc[ni], 0, 0, 0);
            }
        }
        if (it < 31) {
            short* nA = smem[nxt];
            union { short s2[4]; uint64_t u; } p0, p1;
            p0.s2[0] = f2bf(af0.x); p0.s2[1] = f2bf(af0.y); p0.s2[2] = f2bf(af0.z); p0.s2[3] = f2bf(af0.w);
            p1.s2[0] = f2bf(af1.x); p1.s2[1] = f2bf(af1.y); p1.s2[2] = f2bf(af1.z); p1.s2[3] = f2bf(af1.w);
            *(uint64_t*)&nA[arow * 40 + ac4 * 4] = p0.u;
            *(uint64_t*)&nA[(arow + 32) * 40 + ac4 * 4] = p1.u;
        }
        __syncthreads();
    }

    if (w < 2) {
        short* outw = qkv + (size_t)w * TOKENS * HEAD;
        for (int ni = 0; ni < 2; ++ni) {
            int col = wn * 64 + ni * 32 + l31;
            for (int reg = 0; reg < 16; ++reg) {
                int m = (reg & 3) + 8 * (reg >> 2) + 4 * l1;
                outw[(size_t)(m0 + wm * 32 + m) * HEAD + col] = f2bf(acc[ni][reg]);
            }
        }
    } else {
        short* sT = (short*)smem;   // [128 d][stride 72] tokens 0..63
        for (int ni = 0; ni < 2; ++ni) {
            int col = wn * 64 + ni * 32 + l31;
            for (int g = 0; g < 4; ++g) {
                union { short s2[4]; uint64_t u; } pk;
                for (int r = 0; r < 4; ++r) pk.s2[r] = f2bf(acc[ni][g * 4 + r]);
                *(uint64_t*)&sT[col * 72 + wm * 32 + 8 * g + 4 * l1] = pk.u;
            }
        }
        __syncthreads();
        for (int it = 0; it < 4; ++it) {
            int c = it * 256 + t;
            int col = c >> 3, c8 = c & 7;
            uint4 d = *(const uint4*)(&sT[col * 72 + c8 * 8]);
            *(uint4*)(&vT[(size_t)col * TOKENS + m0 + c8 * 8]) = d;
        }
    }
}

// ---------------- kernel 3: flash attention, phase-pipelined DMA staging ----------------
__global__ __launch_bounds__(256)
void attn_kernel(const short* __restrict__ qb, const short* __restrict__ kb,
                 const short* __restrict__ vT, short* __restrict__ po,
                 float* __restrict__ pl) {
    const int bid = blockIdx.x;
    const int b  = bid & 7;
    const int r0 = bid >> 3;        // 0..95
    int qt2 = 0, c0 = 0;
    for (;;) { int sz = (2 * qt2 + 4) / 3; if (r0 < c0 + sz) break; c0 += sz; ++qt2; }
    const int s = r0 - c0;
    const int q0 = qt2 * 128;
    const int nkt = 2 * qt2 + 2;
    const int kt0 = s * 3;
    const int kt1 = (kt0 + 3 < nkt) ? (kt0 + 3) : nkt;

    __shared__ short sK[64 * 128];
    __shared__ short sV[128 * 64];
    __shared__ short sP[128 * 72];

    const int t = threadIdx.x;
    const int wv = t >> 6, lane = t & 63, ln = lane & 15, qd = lane >> 4;
    const int wrow0 = q0 + wv * 32;

    v8s qf[2][4];
    for (int qg = 0; qg < 2; ++qg) {
        const short* qrow = qb + ((size_t)(b * T_SEQ + wrow0 + qg * 16 + ln)) * HEAD;
        for (int ks = 0; ks < 4; ++ks)
            qf[qg][ks] = *(const v8s*)(qrow + ks * 32 + qd * 8);
    }

    const short* kb0 = kb + ((size_t)(b * T_SEQ + kt0 * 64)) * HEAD;
    const short* vb0 = vT + (size_t)(b * T_SEQ + kt0 * 64);
    size_t ksrc[4], vsrc[4];
    short *kdsts[4], *vdsts[4];
    for (int i = 0; i < 4; ++i) {
        int c = (wv * 4 + i) * 64 + lane;
        int krow = c >> 4, ksch = c & 15;
        int kch = (ksch & 8) | ((ksch ^ krow) & 7);
        ksrc[i] = (size_t)krow * HEAD + kch * 8;
        kdsts[i] = &sK[(wv * 4 + i) * 512];
        int dd = c >> 3, vsch = c & 7;
        int vch = (vsch ^ dd) & 7;
        vsrc[i] = (size_t)dd * TOKENS + vch * 8;
        vdsts[i] = &sV[(wv * 4 + i) * 512];
    }

    for (int i = 0; i < 4; ++i) dma16(kb0 + ksrc[i], kdsts[i]);
    for (int i = 0; i < 4; ++i) dma16(vb0 + vsrc[i], vdsts[i]);
    __syncthreads();

    v4f o[2][8] = {};
    float rs[2] = {0.f, 0.f};
    const float sc = 1.4426950408889634f / 11.313708498984761f;  // log2e / sqrt(128)

    for (int kt = kt0; kt < kt1; ++kt) {
        const bool active = (kt * 64 < wrow0 + 32);
        v4f st[2][4] = {};
        if (active) {
            for (int ni = 0; ni < 4; ++ni) {
                int krow = ni * 16 + ln;
                for (int ks = 0; ks < 4; ++ks) {
                    int ch = ks * 4 + qd;
                    v8s kf = *(const v8s*)&sK[krow * 128 + ((ch & 8) | ((ch ^ krow) & 7)) * 8];
                    st[0][ni] = __builtin_amdgcn_mfma_f32_16x16x32_bf16(kf, qf[0][ks], st[0][ni], 0, 0, 0);
                    st[1][ni] = __builtin_amdgcn_mfma_f32_16x16x32_bf16(kf, qf[1][ks], st[1][ni], 0, 0, 0);
                }
            }
        }
        __syncthreads();                       // sK free; drains V-DMA(kt)
        if (kt + 1 < kt1) {
            const short* kbn = kb0 + (size_t)(kt + 1 - kt0) * 64 * HEAD;
            for (int i = 0; i < 4; ++i) dma16(kbn + ksrc[i], kdsts[i]);
        }

        if (active) {
            const bool needMask = (kt * 64 + 63 > wrow0);
            for (int qg = 0; qg < 2; ++qg) {
                int prow = wv * 32 + qg * 16 + ln;
                int qrow_g = wrow0 + qg * 16 + ln;
                for (int ni = 0; ni < 4; ++ni) {
                    union { short s2[4]; uint64_t u; } pk;
                    for (int r = 0; r < 4; ++r) {
                        float p = exp2f(st[qg][ni][r] * sc);
                        int kg = kt * 64 + ni * 16 + qd * 4 + r;
                        if (needMask && kg > qrow_g) p = 0.f;
                        rs[qg] += p;
                        pk.s2[r] = f2bf(p);
                    }
                    *(uint64_t*)(&sP[prow * 72 + ni * 16 + qd * 4]) = pk.u;
                }
            }
            for (int kk2 = 0; kk2 < 2; ++kk2) {
                v8s pf0 = *(const v8s*)&sP[(wv * 32 + ln) * 72 + kk2 * 32 + qd * 8];
                v8s pf1 = *(const v8s*)&sP[(wv * 32 + 16 + ln) * 72 + kk2 * 32 + qd * 8];
                for (int oni = 0; oni < 8; ++oni) {
                    int dd = oni * 16 + ln;
                    int ch = kk2 * 4 + qd;
                    v8s vf = *(const v8s*)&sV[dd * 64 + ((ch ^ dd) & 7) * 8];
                    o[0][oni] = __builtin_amdgcn_mfma_f32_16x16x32_bf16(vf, pf0, o[0][oni], 0, 0, 0);
                    o[1][oni] = __builtin_amdgcn_mfma_f32_16x16x32_bf16(vf, pf1, o[1][oni], 0, 0, 0);
                }
            }
        }
        __syncthreads();                       // sV free; drains K-DMA(kt+1)
        if (kt + 1 < kt1) {
            const short* vbn = vb0 + (kt + 1 - kt0) * 64;
            for (int i = 0; i < 4; ++i) dma16(vbn + vsrc[i], vdsts[i]);
        }
    }

    float lsum[2];
    for (int qg = 0; qg < 2; ++qg) {
        float v = rs[qg];
        v += __shfl_xor(v, 16);
        v += __shfl_xor(v, 32);
        lsum[qg] = v;
    }

    short* pob = po + (size_t)bid * 128 * 128;
    for (int qg = 0; qg < 2; ++qg)
        for (int oni = 0; oni < 8; ++oni) {
            union { short s2[4]; uint2 u; } pk;
            for (int r = 0; r < 4; ++r) pk.s2[r] = f2bf(o[qg][oni][r]);
            *(uint2*)(&pob[(((qg * 8 + oni) * 4 + wv) * 64 + lane) * 4]) = pk.u;
        }
    if (lane < 16)
        for (int qg = 0; qg < 2; ++qg)
            pl[bid * 128 + wv * 32 + qg * 16 + lane] = lsum[qg];
}

// ---------------- kernel 4: combine splits ----------------
__global__ __launch_bounds__(256)
void combine_kernel(const short* __restrict__ po, const float* __restrict__ pl,
                    float* __restrict__ out) {
    const int bid = blockIdx.x;          // 512: b<<6 | qt2<<2 | qh<<1 | dh
    const int dh  = bid & 1;
    const int qh  = (bid >> 1) & 1;
    const int qt2 = (bid >> 2) & 15;
    const int b   = bid >> 6;
    int cum = 0;
    for (int j = 0; j < qt2; ++j) cum += (2 * j + 4) / 3;
    const int S = (2 * qt2 + 4) / 3;

    const int t = threadIdx.x;
    const int wv = t >> 6, lane = t & 63, ln = lane & 15, qd = lane >> 4;

    float l = 0.f;
    float accv[4][4] = {};

    for (int si = 0; si < S; ++si) {
        int slot = (cum + si) * 8 + b;
        l += pl[slot * 128 + wv * 32 + qh * 16 + ln];
        const short* pob = po + (size_t)slot * 16384;
        for (int oi = 0; oi < 4; ++oi) {
            int oni = dh * 4 + oi;
            union { short s2[4]; uint2 u; } pk;
            pk.u = *(const uint2*)(&pob[(((qh * 8 + oni) * 4 + wv) * 64 + lane) * 4]);
            for (int r = 0; r < 4; ++r) accv[oi][r] += bf2f(pk.s2[r]);
        }
    }
    float inv = 1.f / l;
    float* ob = out + ((size_t)(b * T_SEQ) + qt2 * 128 + wv * 32 + qh * 16 + ln) * HEAD;
    for (int oi = 0; oi < 4; ++oi) {
        float4 o4 = make_float4(accv[oi][0] * inv, accv[oi][1] * inv,
                                accv[oi][2] * inv, accv[oi][3] * inv);
        *(float4*)(ob + (dh * 4 + oi) * 16 + qd * 4) = o4;
    }
}

extern "C" void kernel_launch(void* const* d_in, const int* in_sizes, int n_in,
                              void* d_out, int out_size, void* d_ws, size_t ws_size,
                              hipStream_t stream) {
    const float* x  = (const float*)d_in[0];
    const float* Wk = (const float*)d_in[1];
    const float* Wq = (const float*)d_in[2];
    const float* Wv = (const float*)d_in[3];
    float* out = (float*)d_out;

    char* ws = (char*)d_ws;
    short* wt = (short*)ws;                               // 768 KB
    short* qb = (short*)(ws + 0x100000u);                 // 4 MB
    short* kb = (short*)(ws + 0x500000u);                 // 4 MB
    short* vT = (short*)(ws + 0x900000u);                 // 4 MB, [128][16384]
    short* po = (short*)(ws + 0xD00000u);                 // 768*32KB = 24 MB
    float* pl = (float*)(ws + 0x2500000u);                // 768*128 f32
    short* qkv = qb;

    wt_kernel<<<1536, 256, 0, stream>>>(Wq, Wk, Wv, wt);
    qkv_gemm<<<768, 256, 0, stream>>>(x, wt, qkv, vT);
    attn_kernel<<<BATCH * BPB, 256, 0, stream>>>(qb, kb, vT, po, pl);
    combine_kernel<<<512, 256, 0, stream>>>(po, pl, out);
}